// Round 8
// baseline (218.364 us; speedup 1.0000x reference)
//
#include <hip/hip_runtime.h>
#include <hip/hip_bf16.h>

// Problem constants
#define B_    8
#define CIN   256
#define COUT  256
#define H_    128
#define W_    128
#define HP    130   // padded
#define WP    130

// Conv tile: block = 128 oc x (8 rows x 32 cols), 256 thr / 4 waves.
// Wave = 64 oc x (8 rows x 16 cols): m=4 x n=8 frags of 16x16x32.
// KW-phased row sweep; A-frags stream global->regs (no A-LDS, no per-phase
// barriers); X double-buffered in LDS, one barrier per cin-chunk.
#define OCT   128
#define TROWS 8
#define TCOLS 32
#define XROWS 10    // TROWS + 2 halo
#define XCOLS 34    // TCOLS + 2 halo
#define XCH   1360  // 10*34*4 real 16B chunks
#define XCHP  1536  // padded to 6/thread
#define CCS   ((size_t)COUT * CIN)       // element stride per tap j

using bfrag = __attribute__((ext_vector_type(8))) short;   // 8 bf16 (4 VGPRs)
using f32x4 = __attribute__((ext_vector_type(4))) float;   // 4 fp32 acc

#define ASM_VMCNT(n) asm volatile("s_waitcnt vmcnt(" #n ")" ::: "memory")

__device__ __forceinline__ float leaky(float v) {
    return v >= 0.f ? v : 0.2f * v;
}

__device__ __forceinline__ unsigned short to_bf16(float v) {
    __hip_bfloat16 h = __float2bfloat16(v);
    return *(unsigned short*)&h;
}

// ---------------------------------------------------------------------------
// S[i][kw] = sum_{o,kh} weight[o,i,kh,kw]^2          (grid = CIN, 256 thr)
__global__ void compute_S_kernel(const float* __restrict__ weight, float* __restrict__ S) {
    const int i = blockIdx.x;
    const int t = threadIdx.x;     // = o
    const float* wp = weight + ((size_t)t * CIN + i) * 9;
    float s0 = 0.f, s1 = 0.f, s2 = 0.f;
#pragma unroll
    for (int kh = 0; kh < 3; ++kh) {
        float a = wp[kh * 3 + 0], b = wp[kh * 3 + 1], c = wp[kh * 3 + 2];
        s0 = fmaf(a, a, s0); s1 = fmaf(b, b, s1); s2 = fmaf(c, c, s2);
    }
    __shared__ float red[3][256];
    red[0][t] = s0; red[1][t] = s1; red[2][t] = s2;
    __syncthreads();
    for (int off = 128; off > 0; off >>= 1) {
        if (t < off) {
            red[0][t] += red[0][t + off];
            red[1][t] += red[1][t + off];
            red[2][t] += red[2][t + off];
        }
        __syncthreads();
    }
    if (t == 0) {
        S[i * 3 + 0] = red[0][0];
        S[i * 3 + 1] = red[1][0];
        S[i * 3 + 2] = red[2][0];
    }
}

// demod[b][kw] = rsqrt(sum_i style[b,i]^2 * S[i,kw] + 1e-8)   (grid = B)
__global__ void compute_demod_kernel(const float* __restrict__ style,
                                     const float* __restrict__ S,
                                     float* __restrict__ demod) {
    const int b = blockIdx.x;
    const int t = threadIdx.x;     // = i
    float sv = style[b * CIN + t];
    float sv2 = sv * sv;
    float s0 = sv2 * S[t * 3 + 0];
    float s1 = sv2 * S[t * 3 + 1];
    float s2 = sv2 * S[t * 3 + 2];
    __shared__ float red[3][256];
    red[0][t] = s0; red[1][t] = s1; red[2][t] = s2;
    __syncthreads();
    for (int off = 128; off > 0; off >>= 1) {
        if (t < off) {
            red[0][t] += red[0][t + off];
            red[1][t] += red[1][t + off];
            red[2][t] += red[2][t + off];
        }
        __syncthreads();
    }
    if (t == 0) {
        demod[b * 3 + 0] = rsqrtf(red[0][0] + 1e-8f);
        demod[b * 3 + 1] = rsqrtf(red[1][0] + 1e-8f);
        demod[b * 3 + 2] = rsqrtf(red[2][0] + 1e-8f);
    }
}

// wT[b][j][o][i] (bf16) = weight[o][i][j] * style[b][i] * demod[b][j%3]
__global__ void compute_wmodT_kernel(const float* __restrict__ weight,
                                     const float* __restrict__ style,
                                     const float* __restrict__ demod,
                                     unsigned short* __restrict__ wT) {
    const int bx = blockIdx.x;
    const int i  = threadIdx.x;
    const int o  = bx & (COUT - 1);
    const int j  = (bx >> 8) % 9;
    const int b  = bx / (9 * COUT);
    float w = weight[((size_t)o * CIN + i) * 9 + j];
    float m = style[b * CIN + i] * demod[b * 3 + (j % 3)];
    wT[(((size_t)(b * 9 + j) * COUT + o)) * CIN + i] = to_bf16(w * m);
}

// NCHW fp32 -> padded NHWC bf16 (interior): xT[b][h+1][w+1][i] = bf16(x[b][i][h][w])
__global__ __launch_bounds__(256) void transpose_kernel(const float* __restrict__ x,
                                                        unsigned short* __restrict__ xT) {
    const int bx = blockIdx.x;
    const int wtile = (bx & 3) * 32;
    const int itile = (bx >> 2) * 32;
    const int h = blockIdx.y;
    const int b = blockIdx.z;
    const int t = threadIdx.x;

    __shared__ float lt[32][33];

    {   // coalesced read: consecutive t -> consecutive w
        const int tw = t & 31, tr = t >> 5;
#pragma unroll
        for (int rr = 0; rr < 4; ++rr) {
            int il = tr + rr * 8;
            lt[il][tw] = x[(((size_t)b * CIN + itile + il) * H_ + h) * W_ + wtile + tw];
        }
    }
    __syncthreads();
    {   // coalesced write: consecutive t -> consecutive i
        const int il = t & 31, wr = t >> 5;
#pragma unroll
        for (int rr = 0; rr < 4; ++rr) {
            int wl = wr + rr * 8;
            xT[(((size_t)b * HP + (h + 1)) * WP + (wtile + wl + 1)) * CIN + itile + il] =
                to_bf16(lt[il][wl]);
        }
    }
}

// Zero only the padded border of xT.
__global__ void zero_border_kernel(unsigned short* __restrict__ xT) {
    const int b = blockIdx.x;
    const int r = blockIdx.y;
    const int t = threadIdx.x;
    int npix, base, stride;
    if (r == 0)      { npix = WP;  base = 0;                 stride = 1;  }
    else if (r == 1) { npix = WP;  base = (HP - 1) * WP;     stride = 1;  }
    else if (r == 2) { npix = 128; base = WP;                stride = WP; }
    else             { npix = 128; base = WP + (WP - 1);     stride = WP; }
    for (int idx = t; idx < npix * 32; idx += 256) {
        int p = idx >> 5, q = idx & 31;
        size_t off = ((size_t)b * HP * WP + base + (size_t)p * stride) * CIN;
        *(int4*)((unsigned short*)xT + off + q * 8) = (int4){0, 0, 0, 0};
    }
}

// ---------------------------------------------------------------------------
// Implicit-GEMM conv + leaky relu, barrier-light:
// - A-frags (12 x 16B/wave/phase) load global->regs, streamed IN PLACE: set
//   aF[kh] is dead after sweep row 7+kh, reloaded there for the next phase
//   (~1000 cy MFMA cover vs ~200-400 cy L2 latency; wT is L2/L1-hot).
// - X [10][34][32i] double-buffered via global_load_lds; staged once per
//   cin-chunk during the kw2 sweep.
// - ONE barrier per chunk (was 6): waves drift across the 288-MFMA span,
//   so the 8 waves/CU anti-phase and LDS/VMEM hide under the MFMA pipe.
__global__ __launch_bounds__(256, 2) void conv_mfma_kernel(
    const unsigned short* __restrict__ xT,   // [8][130][130][256] bf16
    const unsigned short* __restrict__ wT,   // [8][9][256][256]  bf16
    float* __restrict__ out)
{
    const int tid = threadIdx.x;
    const int lin = blockIdx.x;               // 1024 blocks; lin&7 -> XCD = batch
    const int b    = lin & 7;
    const int rest = lin >> 3;                // 0..127
    const int oc0  = (rest & 1) * OCT;
    const int w0   = ((rest >> 1) & 3) * TCOLS;
    const int h0   = (rest >> 3) * TROWS;

    const int wid   = tid >> 6;               // 0..3
    const int lane  = tid & 63;
    const int wm    = wid >> 1;               // oc half (64 oc)
    const int cw    = wid & 1;                // col half (16 cols)
    const int l15   = lane & 15;
    const int khalf = lane >> 4;              // k-group 0..3

    __shared__ unsigned short lds_x[2][XCHP * 8];   // 2 x 24576 B

    const unsigned short* xb = xT + ((size_t)(b * HP + h0) * WP + w0) * CIN;
    // per-wave A base (includes oc0 + wm*64) and per-lane offset
    const unsigned short* wbw = wT + ((size_t)(b * 9) * COUT + oc0 + wm * 64) * CIN;
    const size_t alane = (size_t)l15 * CIN + khalf * 8;

    f32x4 acc[4][8];
#pragma unroll
    for (int m = 0; m < 4; ++m)
#pragma unroll
        for (int n = 0; n < 8; ++n) acc[m][n] = (f32x4){0.f, 0.f, 0.f, 0.f};

    bfrag aF[3][4];      // current phase's 12 A-frags (streamed in place)

    // X-stage: 6 global_load_lds per thread into dst buffer (src swizzled)
    auto stage_X = [&](int i0, unsigned short* dst) {
#pragma unroll
        for (int j = 0; j < 6; ++j) {
            int g  = (wid * 6 + j) * 64 + lane;        // [0,1536)
            int gg = g < XCH ? g : 0;                  // clamp dummies
            int pix = gg >> 2, slot = gg & 3;
            int row = pix / XCOLS, col = pix - row * XCOLS;
            int ofx = (row * WP + col) * CIN + ((slot ^ ((col >> 1) & 3)) << 3);
            __builtin_amdgcn_global_load_lds(
                (const __attribute__((address_space(1))) void*)(xb + ofx + i0),
                (__attribute__((address_space(3))) void*)(dst + (wid * 6 + j) * 512),
                16, 0, 0);
        }
    };

    // row sweep for one kw phase; `an` = A base for the NEXT phase
    // (wbw + kw'*CCS + i0'); aF[kh] reloaded in place at row 7+kh.
    auto sweep = [&](int kw, const unsigned short* xcur, const unsigned short* an) {
        const int col = cw * 16 + l15 + kw;
        const unsigned short* bp =
            xcur + col * 32 + ((khalf ^ ((col >> 1) & 3)) << 3);

        bfrag bs[3];
        bs[0] = *(const bfrag*)(bp);
        bs[1] = *(const bfrag*)(bp + (size_t)XCOLS * 32);

#pragma unroll
        for (int r = 0; r < 10; ++r) {
            if (r < 8)
                bs[(r + 2) % 3] = *(const bfrag*)(bp + (size_t)(r + 2) * XCOLS * 32);
            const bfrag bv = bs[r % 3];
#pragma unroll
            for (int kh = 0; kh < 3; ++kh) {
                const int n = r - kh;
                if (n >= 0 && n < 8) {
#pragma unroll
                    for (int m = 0; m < 4; ++m)
                        acc[m][n] = __builtin_amdgcn_mfma_f32_16x16x32_bf16(
                            aF[kh][m], bv, acc[m][n], 0, 0, 0);
                }
            }
            if (r >= 7) {   // aF[r-7] now dead: reload for next phase
                const int kh = r - 7;
#pragma unroll
                for (int m = 0; m < 4; ++m)
                    aF[kh][m] = *(const bfrag*)(an + (size_t)(kh * 3) * CCS
                                                + (size_t)(m * 16) * CIN + alane);
            }
        }
    };

    // ---- prologue: X(0) -> buf0; initial A(kw0, c0) frags; drain; barrier
    stage_X(0, lds_x[0]);
#pragma unroll
    for (int kh = 0; kh < 3; ++kh)
#pragma unroll
        for (int m = 0; m < 4; ++m)
            aF[kh][m] = *(const bfrag*)(wbw + (size_t)(kh * 3) * CCS
                                        + (size_t)(m * 16) * CIN + alane);
    ASM_VMCNT(0);
    __builtin_amdgcn_s_barrier();
    __builtin_amdgcn_sched_barrier(0);

#pragma unroll 1
    for (int c = 0; c < 8; ++c) {
        const unsigned short* xcur = lds_x[c & 1];
        const size_t i0  = (size_t)c * 32;
        const size_t i0n = (size_t)((c + 1) & 7) * 32;   // c=7 -> dummy chunk 0

        sweep(0, xcur, wbw + 1 * CCS + i0);     // streams A(kw1, c)
        sweep(1, xcur, wbw + 2 * CCS + i0);     // streams A(kw2, c)
        if (c < 7) stage_X((int)i0n, lds_x[(c + 1) & 1]);   // X(c+1) -> other buf
        sweep(2, xcur, wbw + i0n);              // streams A(kw0, c+1) (dummy at c=7)
        // queue (oldest first): X(6, if issued) then A(12). Drain X, keep A.
        ASM_VMCNT(12);
        __builtin_amdgcn_s_barrier();
        __builtin_amdgcn_sched_barrier(0);
    }
    ASM_VMCNT(0);   // drain tail dummy A-loads

    // ---- epilogue: leaky relu + store (C/D: col=lane&15 -> pixel, row -> oc)
#pragma unroll
    for (int m = 0; m < 4; ++m) {
#pragma unroll
        for (int n = 0; n < 8; ++n) {
            int h = h0 + n;
            int w = w0 + cw * 16 + l15;
#pragma unroll
            for (int r = 0; r < 4; ++r) {
                int oc = oc0 + wm * 64 + m * 16 + khalf * 4 + r;
                out[(((size_t)b * COUT + oc) * H_ + h) * W_ + w] = leaky(acc[m][n][r]);
            }
        }
    }
}

// ---------------------------------------------------------------------------
extern "C" void kernel_launch(void* const* d_in, const int* in_sizes, int n_in,
                              void* d_out, int out_size, void* d_ws, size_t ws_size,
                              hipStream_t stream) {
    const float* x      = (const float*)d_in[0];  // (8,256,128,128)
    const float* style  = (const float*)d_in[1];  // (8,256)
    const float* weight = (const float*)d_in[2];  // (256,256,3,3)
    float* out = (float*)d_out;                   // (8,256,128,128)

    // ws layout: S f32[768] @0 | demod f32[24] @4096 | wT bf16 @8192 (9.4MB)
    //            | xTpad bf16 @9445376 (69.2MB)   -> total ~78.7 MB
    float* S     = (float*)d_ws;
    float* demod = (float*)((char*)d_ws + 4096);
    unsigned short* wT = (unsigned short*)((char*)d_ws + 8192);
    unsigned short* xT = (unsigned short*)((char*)d_ws + 9445376);

    compute_S_kernel<<<CIN, 256, 0, stream>>>(weight, S);
    compute_demod_kernel<<<B_, 256, 0, stream>>>(style, S, demod);
    compute_wmodT_kernel<<<B_ * 9 * COUT, 256, 0, stream>>>(weight, style, demod, wT);
    transpose_kernel<<<dim3(32, H_, B_), 256, 0, stream>>>(x, xT);
    zero_border_kernel<<<dim3(B_, 4), 256, 0, stream>>>(xT);

    conv_mfma_kernel<<<dim3(1024), 256, 0, stream>>>(xT, wT, out);
}

// Round 9
// 202.505 us; speedup vs baseline: 1.0783x; 1.0783x over previous
//
#include <hip/hip_runtime.h>
#include <hip/hip_bf16.h>

// Problem constants
#define B_    8
#define CIN   256
#define COUT  256
#define H_    128
#define W_    128
#define HP    130   // padded
#define WP    130

// Conv tile: block = 128 oc x (8 rows x 32 cols), 256 thr / 4 waves.
// Wave = 64 oc x (8 rows x 16 cols). MFMA 32x32x16: m=2 oc-tiles x np=4
// row-pair px-tiles (px = 16 cols x rows {np, np+4}).
// Phases per-KW: A[3kh][128oc][32i] dbuf (gload_lds, counted vmcnt);
// X [10][34][32i] single-buffered, staged at chunk boundary.
#define OCT   128
#define TROWS 8
#define TCOLS 32
#define XROWS 10    // TROWS + 2 halo
#define XCOLS 34    // TCOLS + 2 halo
#define XCH   1360  // 10*34*4 real 16B chunks
#define XCHP  1536  // padded to 6/thread
#define CCS   ((size_t)COUT * CIN)       // element stride per tap j

using bfrag  = __attribute__((ext_vector_type(8))) short;   // 8 bf16 (4 VGPRs)
using f32x16 = __attribute__((ext_vector_type(16))) float;  // 16 fp32 acc

#define ASM_VMCNT(n) asm volatile("s_waitcnt vmcnt(" #n ")" ::: "memory")
#define ASM_LGKM0()  asm volatile("s_waitcnt lgkmcnt(0)" ::: "memory")

__device__ __forceinline__ float leaky(float v) {
    return v >= 0.f ? v : 0.2f * v;
}

__device__ __forceinline__ unsigned short to_bf16(float v) {
    __hip_bfloat16 h = __float2bfloat16(v);
    return *(unsigned short*)&h;
}

// ---------------------------------------------------------------------------
// S[i][kw] = sum_{o,kh} weight[o,i,kh,kw]^2          (grid = CIN, 256 thr)
__global__ void compute_S_kernel(const float* __restrict__ weight, float* __restrict__ S) {
    const int i = blockIdx.x;
    const int t = threadIdx.x;     // = o
    const float* wp = weight + ((size_t)t * CIN + i) * 9;
    float s0 = 0.f, s1 = 0.f, s2 = 0.f;
#pragma unroll
    for (int kh = 0; kh < 3; ++kh) {
        float a = wp[kh * 3 + 0], b = wp[kh * 3 + 1], c = wp[kh * 3 + 2];
        s0 = fmaf(a, a, s0); s1 = fmaf(b, b, s1); s2 = fmaf(c, c, s2);
    }
    __shared__ float red[3][256];
    red[0][t] = s0; red[1][t] = s1; red[2][t] = s2;
    __syncthreads();
    for (int off = 128; off > 0; off >>= 1) {
        if (t < off) {
            red[0][t] += red[0][t + off];
            red[1][t] += red[1][t + off];
            red[2][t] += red[2][t + off];
        }
        __syncthreads();
    }
    if (t == 0) {
        S[i * 3 + 0] = red[0][0];
        S[i * 3 + 1] = red[1][0];
        S[i * 3 + 2] = red[2][0];
    }
}

// demod[b][kw] = rsqrt(sum_i style[b,i]^2 * S[i,kw] + 1e-8)   (grid = B)
__global__ void compute_demod_kernel(const float* __restrict__ style,
                                     const float* __restrict__ S,
                                     float* __restrict__ demod) {
    const int b = blockIdx.x;
    const int t = threadIdx.x;     // = i
    float sv = style[b * CIN + t];
    float sv2 = sv * sv;
    float s0 = sv2 * S[t * 3 + 0];
    float s1 = sv2 * S[t * 3 + 1];
    float s2 = sv2 * S[t * 3 + 2];
    __shared__ float red[3][256];
    red[0][t] = s0; red[1][t] = s1; red[2][t] = s2;
    __syncthreads();
    for (int off = 128; off > 0; off >>= 1) {
        if (t < off) {
            red[0][t] += red[0][t + off];
            red[1][t] += red[1][t + off];
            red[2][t] += red[2][t + off];
        }
        __syncthreads();
    }
    if (t == 0) {
        demod[b * 3 + 0] = rsqrtf(red[0][0] + 1e-8f);
        demod[b * 3 + 1] = rsqrtf(red[1][0] + 1e-8f);
        demod[b * 3 + 2] = rsqrtf(red[2][0] + 1e-8f);
    }
}

// wT[b][j][o][i] (bf16) = weight[o][i][j] * style[b][i] * demod[b][j%3]
__global__ void compute_wmodT_kernel(const float* __restrict__ weight,
                                     const float* __restrict__ style,
                                     const float* __restrict__ demod,
                                     unsigned short* __restrict__ wT) {
    const int bx = blockIdx.x;
    const int i  = threadIdx.x;
    const int o  = bx & (COUT - 1);
    const int j  = (bx >> 8) % 9;
    const int b  = bx / (9 * COUT);
    float w = weight[((size_t)o * CIN + i) * 9 + j];
    float m = style[b * CIN + i] * demod[b * 3 + (j % 3)];
    wT[(((size_t)(b * 9 + j) * COUT + o)) * CIN + i] = to_bf16(w * m);
}

// NCHW fp32 -> padded NHWC bf16 (interior) + border zero (y-slice H_).
// grid = dim3(32, H_+1, B_), 256 thr.
__global__ __launch_bounds__(256) void transpose_kernel(const float* __restrict__ x,
                                                        unsigned short* __restrict__ xT) {
    const int bx = blockIdx.x;
    const int h  = blockIdx.y;
    const int b  = blockIdx.z;
    const int t  = threadIdx.x;
    const int itile = (bx >> 2) * 32;

    if (h == H_) {
        // border: 516 px split 4 ways by (bx&3); 32 ch (itile) per block
        const int q = bx & 3;
        for (int idx = t; idx < 129 * 4; idx += 256) {
            int px_i = idx >> 2, q4 = idx & 3;
            int p = q * 129 + px_i;
            int row, col;
            if (p < 130)      { row = 0;       col = p; }
            else if (p < 260) { row = HP - 1;  col = p - 130; }
            else if (p < 388) { row = p - 259; col = 0; }
            else              { row = p - 387; col = WP - 1; }
            size_t off = ((size_t)b * HP * WP + (size_t)row * WP + col) * CIN
                         + itile + q4 * 8;
            *(int4*)((unsigned short*)xT + off) = (int4){0, 0, 0, 0};
        }
        return;
    }

    const int wtile = (bx & 3) * 32;
    __shared__ float lt[32][33];
    {   // coalesced read: consecutive t -> consecutive w
        const int tw = t & 31, tr = t >> 5;
#pragma unroll
        for (int rr = 0; rr < 4; ++rr) {
            int il = tr + rr * 8;
            lt[il][tw] = x[(((size_t)b * CIN + itile + il) * H_ + h) * W_ + wtile + tw];
        }
    }
    __syncthreads();
    {   // coalesced write: consecutive t -> consecutive i
        const int il = t & 31, wr = t >> 5;
#pragma unroll
        for (int rr = 0; rr < 4; ++rr) {
            int wl = wr + rr * 8;
            xT[(((size_t)b * HP + (h + 1)) * WP + (wtile + wl + 1)) * CIN + itile + il] =
                to_bf16(lt[il][wl]);
        }
    }
}

// ---------------------------------------------------------------------------
// Implicit-GEMM conv + leaky relu, 32x32x16 MFMA, KW-phased row-pair sweep.
__global__ __launch_bounds__(256, 2) void conv_mfma_kernel(
    const unsigned short* __restrict__ xT,   // [8][130][130][256] bf16
    const unsigned short* __restrict__ wT,   // [8][9][256][256]  bf16
    float* __restrict__ out)
{
    const int tid = threadIdx.x;
    const int lin = blockIdx.x;               // 1024 blocks; lin&7 -> XCD = batch
    const int b    = lin & 7;
    const int rest = lin >> 3;                // 0..127
    const int oc0  = (rest & 1) * OCT;
    const int w0   = ((rest >> 1) & 3) * TCOLS;
    const int h0   = (rest >> 3) * TROWS;

    const int wid  = tid >> 6;                // 0..3
    const int lane = tid & 63;
    const int wm   = wid >> 1;                // oc half (64 oc)
    const int cw   = wid & 1;                 // col half (16 cols)
    const int l15  = lane & 15;
    const int l31  = lane & 31;
    const int ksl  = lane >> 5;               // k-half-of-frag selector (0/1)
    const int rowoff = ((lane >> 4) & 1) * 4; // B px row-pair offset

    __shared__ unsigned short lds_a[2][3 * OCT * 32];   // 2 x 24576 B ([kh][o][i])
    __shared__ unsigned short lds_x[XCHP * 8];          // 24576 B (incl pad)

    const unsigned short* xb = xT + ((size_t)(b * HP + h0) * WP + w0) * CIN;
    const unsigned short* wb = wT + ((size_t)(b * 9) * COUT + oc0) * CIN;

    // ---- per-thread gload source offsets (swizzled) ----
    int offA[6];
#pragma unroll
    for (int j = 0; j < 6; ++j) {
        int c    = (wid * 6 + j) * 64 + lane;          // [0,1536)
        int slot = c & 3;
        int o    = (c >> 2) & 127;
        int kh   = c >> 9;
        offA[j] = (int)((size_t)(kh * 3) * CCS) + o * CIN
                  + ((slot ^ ((o >> 1) & 3)) << 3);
    }

    f32x16 acc[2][4];
#pragma unroll
    for (int m = 0; m < 2; ++m)
#pragma unroll
        for (int n = 0; n < 4; ++n)
#pragma unroll
            for (int e = 0; e < 16; ++e) acc[m][n][e] = 0.f;

    auto stage_A = [&](unsigned short* dst, const unsigned short* wsrc) {
#pragma unroll
        for (int j = 0; j < 6; ++j) {
            __builtin_amdgcn_global_load_lds(
                (const __attribute__((address_space(1))) void*)(wsrc + offA[j]),
                (__attribute__((address_space(3))) void*)(dst + (wid * 6 + j) * 512),
                16, 0, 0);
        }
    };
    auto stage_X = [&](int i0) {
#pragma unroll
        for (int j = 0; j < 6; ++j) {
            int g  = (wid * 6 + j) * 64 + lane;        // [0,1536)
            int gg = g < XCH ? g : 0;                  // clamp dummies
            int pix = gg >> 2, slot = gg & 3;
            int row = pix / XCOLS, col = pix - row * XCOLS;
            int ofx = (row * WP + col) * CIN + ((slot ^ ((col >> 1) & 3)) << 3);
            __builtin_amdgcn_global_load_lds(
                (const __attribute__((address_space(1))) void*)(xb + ofx + i0),
                (__attribute__((address_space(3))) void*)(lds_x + (wid * 6 + j) * 512),
                16, 0, 0);
        }
    };

    // A-frag base: oc row = lane&31 within 32-oc tile; XOR by ((oc>>1)&3)
    const int axor = (l31 >> 1) & 3;
    const int abase = (wm * 64 + l31) * 32;   // + (m*32)*32 + kh*128*32

    // kw-phase compute: 12 A-frag reads (3kh x 2m x 2ksub), row-pair sweep
    // r=0..5 reading 2 B-frags each (12 reads), 48 MFMA.
    auto compute = [&](int kw, const unsigned short* ab) {
        const int col  = cw * 16 + l15 + kw;
        const int bxor = (col >> 1) & 3;
        const unsigned short* bp0 =
            lds_x + ((rowoff) * XCOLS + col) * 32 + (((0 * 2 + ksl) ^ bxor) << 3);
        const unsigned short* bp1 =
            lds_x + ((rowoff) * XCOLS + col) * 32 + (((1 * 2 + ksl) ^ bxor) << 3);

        bfrag aF[3][2][2];
#pragma unroll
        for (int kh = 0; kh < 3; ++kh)
#pragma unroll
            for (int m = 0; m < 2; ++m)
#pragma unroll
                for (int ks = 0; ks < 2; ++ks)
                    aF[kh][m][ks] = *(const bfrag*)(ab + kh * (OCT * 32) + abase
                                      + m * (32 * 32) + (((ks * 2 + ksl) ^ axor) << 3));

        bfrag bs[2][2];   // [r parity][ksub]
        bs[0][0] = *(const bfrag*)(bp0);
        bs[0][1] = *(const bfrag*)(bp1);

        __builtin_amdgcn_s_setprio(1);
#pragma unroll
        for (int r = 0; r < 6; ++r) {
            if (r < 5) {
                bs[(r + 1) & 1][0] = *(const bfrag*)(bp0 + (size_t)(r + 1) * XCOLS * 32);
                bs[(r + 1) & 1][1] = *(const bfrag*)(bp1 + (size_t)(r + 1) * XCOLS * 32);
            }
#pragma unroll
            for (int kh = 0; kh < 3; ++kh) {
                const int np = r - kh;
                if (np >= 0 && np < 4) {
#pragma unroll
                    for (int m = 0; m < 2; ++m) {
                        acc[m][np] = __builtin_amdgcn_mfma_f32_32x32x16_bf16(
                            aF[kh][m][0], bs[r & 1][0], acc[m][np], 0, 0, 0);
                        acc[m][np] = __builtin_amdgcn_mfma_f32_32x32x16_bf16(
                            aF[kh][m][1], bs[r & 1][1], acc[m][np], 0, 0, 0);
                    }
                }
            }
        }
        __builtin_amdgcn_s_setprio(0);
    };

    // ---- prologue: X(0) + A(kw0,c0); drain; barrier
    stage_X(0);
    stage_A(lds_a[0], wb);
    ASM_VMCNT(0);
    __builtin_amdgcn_s_barrier();
    __builtin_amdgcn_sched_barrier(0);

    // Per chunk: 4 barriers. kw0 start: vmcnt(6) drains X(c) (A kept in
    // flight); each phase end: lgkm0 + vmcnt(0) (A issued a full compute
    // earlier -> free) + barrier; X(c+1) issued right after kw2's barrier.
#pragma unroll 1
    for (int c = 0; c < 8; ++c) {
        unsigned short* pa = lds_a[c & 1];
        unsigned short* pb = lds_a[(c & 1) ^ 1];
        const size_t i0  = (size_t)c * 32;
        const size_t i0n = (size_t)((c + 1) & 7) * 32;  // c=7 -> dummy chunk 0

        // kw0
        stage_A(pb, wb + 1 * CCS + i0);
        ASM_VMCNT(6);
        __builtin_amdgcn_s_barrier();
        __builtin_amdgcn_sched_barrier(0);
        compute(0, pa);
        ASM_LGKM0(); ASM_VMCNT(0);
        __builtin_amdgcn_s_barrier();
        __builtin_amdgcn_sched_barrier(0);
        // kw1
        stage_A(pa, wb + 2 * CCS + i0);
        compute(1, pb);
        ASM_LGKM0(); ASM_VMCNT(0);
        __builtin_amdgcn_s_barrier();
        __builtin_amdgcn_sched_barrier(0);
        // kw2
        stage_A(pb, wb + i0n);               // A(kw0, c+1); dummy at c=7
        compute(2, pa);
        ASM_LGKM0(); ASM_VMCNT(0);
        __builtin_amdgcn_s_barrier();
        __builtin_amdgcn_sched_barrier(0);
        if (c < 7) stage_X((int)i0n);        // X(c+1): buffer free post-barrier
    }
    ASM_VMCNT(0);   // drain tail dummy

    // ---- epilogue: leaky relu + store
    // C/D 32x32: col(lane&31) -> px (col l15, row-pair lane>>4&1);
    // row = (reg&3)+8*(reg>>2)+4*(lane>>5) -> oc within 32-tile.
#pragma unroll
    for (int m = 0; m < 2; ++m) {
#pragma unroll
        for (int np = 0; np < 4; ++np) {
            int h = h0 + np + rowoff;
            int w = w0 + cw * 16 + l15;
#pragma unroll
            for (int r = 0; r < 16; ++r) {
                int oc = oc0 + wm * 64 + m * 32 + ((r & 3) + 8 * (r >> 2) + 4 * ksl);
                out[(((size_t)b * COUT + oc) * H_ + h) * W_ + w] = leaky(acc[m][np][r]);
            }
        }
    }
}

// ---------------------------------------------------------------------------
extern "C" void kernel_launch(void* const* d_in, const int* in_sizes, int n_in,
                              void* d_out, int out_size, void* d_ws, size_t ws_size,
                              hipStream_t stream) {
    const float* x      = (const float*)d_in[0];  // (8,256,128,128)
    const float* style  = (const float*)d_in[1];  // (8,256)
    const float* weight = (const float*)d_in[2];  // (256,256,3,3)
    float* out = (float*)d_out;                   // (8,256,128,128)

    // ws layout: S f32[768] @0 | demod f32[24] @4096 | wT bf16 @8192 (9.4MB)
    //            | xTpad bf16 @9445376 (69.2MB)   -> total ~78.7 MB
    float* S     = (float*)d_ws;
    float* demod = (float*)((char*)d_ws + 4096);
    unsigned short* wT = (unsigned short*)((char*)d_ws + 8192);
    unsigned short* xT = (unsigned short*)((char*)d_ws + 9445376);

    compute_S_kernel<<<CIN, 256, 0, stream>>>(weight, S);
    compute_demod_kernel<<<B_, 256, 0, stream>>>(style, S, demod);
    compute_wmodT_kernel<<<B_ * 9 * COUT, 256, 0, stream>>>(weight, style, demod, wT);
    transpose_kernel<<<dim3(32, H_ + 1, B_), 256, 0, stream>>>(x, xT);

    conv_mfma_kernel<<<dim3(1024), 256, 0, stream>>>(xT, wT, out);
}

// Round 12
// 185.539 us; speedup vs baseline: 1.1769x; 1.0914x over previous
//
#include <hip/hip_runtime.h>
#include <hip/hip_bf16.h>

// Problem constants
#define B_    8
#define CIN   256
#define COUT  256
#define H_    128
#define W_    128
#define HP    130   // padded
#define WP    130

// Conv tile: block = 128 oc x (8 rows x 32 cols), 256 thr / 4 waves.
// Wave = 64 oc x (8 rows x 16 cols): m=4 x n=8 frags of 16x16x32.
// KW-phases p=3c+kw, tile t=p lives in buf[t%2]. Phase p:
//   stage tile(p+2) -> buf[p%2]   (WAR-safe: buf[p%2]'s readers = phase
//                                  p-1's mid-sweep, retired by its LGKM0+BAR)
//   compute(p): aF regs hold tile p; rows 7-9 reload aF <- tile(p+1) from
//               buf[(p+1)%2]      (RAW-safe: staged at p-1, drained by p-1's
//                                  end vmcnt(0)+BAR -> all waves)
//   LGKM0; vmcnt(0); BAR          (vmcnt(0) ~free: stage issued ~2000cy ago)
// 4 barriers/chunk; zero exposed A-burst at phase start.
#define OCT   128
#define TROWS 8
#define TCOLS 32
#define XROWS 10    // TROWS + 2 halo
#define XCOLS 34    // TCOLS + 2 halo
#define XCH   1360  // 10*34*4 real 16B chunks
#define XCHP  1536  // padded to 6/thread
#define CCS   ((size_t)COUT * CIN)       // element stride per tap j

using bfrag = __attribute__((ext_vector_type(8))) short;   // 8 bf16 (4 VGPRs)
using f32x4 = __attribute__((ext_vector_type(4))) float;   // 4 fp32 acc

#define ASM_VMCNT(n) asm volatile("s_waitcnt vmcnt(" #n ")" ::: "memory")
#define ASM_LGKM0()  asm volatile("s_waitcnt lgkmcnt(0)" ::: "memory")
#define BAR()  do { __builtin_amdgcn_s_barrier(); __builtin_amdgcn_sched_barrier(0); } while (0)

__device__ __forceinline__ float leaky(float v) {
    return v >= 0.f ? v : 0.2f * v;
}

__device__ __forceinline__ unsigned short to_bf16(float v) {
    __hip_bfloat16 h = __float2bfloat16(v);
    return *(unsigned short*)&h;
}

// ---------------------------------------------------------------------------
// S[i][kw] = sum_{o,kh} weight[o,i,kh,kw]^2          (grid = CIN, 256 thr)
__global__ void compute_S_kernel(const float* __restrict__ weight, float* __restrict__ S) {
    const int i = blockIdx.x;
    const int t = threadIdx.x;     // = o
    const float* wp = weight + ((size_t)t * CIN + i) * 9;
    float s0 = 0.f, s1 = 0.f, s2 = 0.f;
#pragma unroll
    for (int kh = 0; kh < 3; ++kh) {
        float a = wp[kh * 3 + 0], b = wp[kh * 3 + 1], c = wp[kh * 3 + 2];
        s0 = fmaf(a, a, s0); s1 = fmaf(b, b, s1); s2 = fmaf(c, c, s2);
    }
    __shared__ float red[3][256];
    red[0][t] = s0; red[1][t] = s1; red[2][t] = s2;
    __syncthreads();
    for (int off = 128; off > 0; off >>= 1) {
        if (t < off) {
            red[0][t] += red[0][t + off];
            red[1][t] += red[1][t + off];
            red[2][t] += red[2][t + off];
        }
        __syncthreads();
    }
    if (t == 0) {
        S[i * 3 + 0] = red[0][0];
        S[i * 3 + 1] = red[1][0];
        S[i * 3 + 2] = red[2][0];
    }
}

// demod[b][kw] = rsqrt(sum_i style[b,i]^2 * S[i,kw] + 1e-8)   (grid = B)
__global__ void compute_demod_kernel(const float* __restrict__ style,
                                     const float* __restrict__ S,
                                     float* __restrict__ demod) {
    const int b = blockIdx.x;
    const int t = threadIdx.x;     // = i
    float sv = style[b * CIN + t];
    float sv2 = sv * sv;
    float s0 = sv2 * S[t * 3 + 0];
    float s1 = sv2 * S[t * 3 + 1];
    float s2 = sv2 * S[t * 3 + 2];
    __shared__ float red[3][256];
    red[0][t] = s0; red[1][t] = s1; red[2][t] = s2;
    __syncthreads();
    for (int off = 128; off > 0; off >>= 1) {
        if (t < off) {
            red[0][t] += red[0][t + off];
            red[1][t] += red[1][t + off];
            red[2][t] += red[2][t + off];
        }
        __syncthreads();
    }
    if (t == 0) {
        demod[b * 3 + 0] = rsqrtf(red[0][0] + 1e-8f);
        demod[b * 3 + 1] = rsqrtf(red[1][0] + 1e-8f);
        demod[b * 3 + 2] = rsqrtf(red[2][0] + 1e-8f);
    }
}

// wT[b][j][o][i] (bf16) = weight[o][i][j] * style[b][i] * demod[b][j%3]
__global__ void compute_wmodT_kernel(const float* __restrict__ weight,
                                     const float* __restrict__ style,
                                     const float* __restrict__ demod,
                                     unsigned short* __restrict__ wT) {
    const int bx = blockIdx.x;
    const int i  = threadIdx.x;
    const int o  = bx & (COUT - 1);
    const int j  = (bx >> 8) % 9;
    const int b  = bx / (9 * COUT);
    float w = weight[((size_t)o * CIN + i) * 9 + j];
    float m = style[b * CIN + i] * demod[b * 3 + (j % 3)];
    wT[(((size_t)(b * 9 + j) * COUT + o)) * CIN + i] = to_bf16(w * m);
}

// NCHW fp32 -> padded NHWC bf16 (interior) + border zero (y-slice H_).
// grid = dim3(32, H_+1, B_), 256 thr.
__global__ __launch_bounds__(256) void transpose_kernel(const float* __restrict__ x,
                                                        unsigned short* __restrict__ xT) {
    const int bx = blockIdx.x;
    const int h  = blockIdx.y;
    const int b  = blockIdx.z;
    const int t  = threadIdx.x;
    const int itile = (bx >> 2) * 32;

    if (h == H_) {
        // border: 516 px split 4 ways by (bx&3); 32 ch (itile) per block
        const int q = bx & 3;
        for (int idx = t; idx < 129 * 4; idx += 256) {
            int px_i = idx >> 2, q4 = idx & 3;
            int p = q * 129 + px_i;
            int row, col;
            if (p < 130)      { row = 0;       col = p; }
            else if (p < 260) { row = HP - 1;  col = p - 130; }
            else if (p < 388) { row = p - 259; col = 0; }
            else              { row = p - 387; col = WP - 1; }
            size_t off = ((size_t)b * HP * WP + (size_t)row * WP + col) * CIN
                         + itile + q4 * 8;
            *(int4*)((unsigned short*)xT + off) = (int4){0, 0, 0, 0};
        }
        return;
    }

    const int wtile = (bx & 3) * 32;
    __shared__ float lt[32][33];
    {   // coalesced read: consecutive t -> consecutive w
        const int tw = t & 31, tr = t >> 5;
#pragma unroll
        for (int rr = 0; rr < 4; ++rr) {
            int il = tr + rr * 8;
            lt[il][tw] = x[(((size_t)b * CIN + itile + il) * H_ + h) * W_ + wtile + tw];
        }
    }
    __syncthreads();
    {   // coalesced write: consecutive t -> consecutive i
        const int il = t & 31, wr = t >> 5;
#pragma unroll
        for (int rr = 0; rr < 4; ++rr) {
            int wl = wr + rr * 8;
            xT[(((size_t)b * HP + (h + 1)) * WP + (wtile + wl + 1)) * CIN + itile + il] =
                to_bf16(lt[il][wl]);
        }
    }
}

// ---------------------------------------------------------------------------
// Implicit-GEMM conv + leaky relu; KW-phased, end-drained 2-buffer A-pipeline.
__global__ __launch_bounds__(256, 2) void conv_mfma_kernel(
    const unsigned short* __restrict__ xT,   // [8][130][130][256] bf16
    const unsigned short* __restrict__ wT,   // [8][9][256][256]  bf16
    float* __restrict__ out)
{
    const int tid = threadIdx.x;
    const int lin = blockIdx.x;               // 1024 blocks; lin&7 -> XCD = batch
    const int b    = lin & 7;
    const int rest = lin >> 3;                // 0..127
    const int oc0  = (rest & 1) * OCT;
    const int w0   = ((rest >> 1) & 3) * TCOLS;
    const int h0   = (rest >> 3) * TROWS;

    const int wid   = tid >> 6;               // 0..3
    const int lane  = tid & 63;
    const int wm    = wid >> 1;               // oc half (64 oc)
    const int cw    = wid & 1;                // col half (16 cols)
    const int l15   = lane & 15;
    const int khalf = lane >> 4;              // k-group 0..3

    __shared__ unsigned short lds_a[2][3 * OCT * 32];   // 2 x 24576 B ([kh][o][i])
    __shared__ unsigned short lds_x[XCHP * 8];          // 24576 B (incl pad)

    const unsigned short* xb = xT + ((size_t)(b * HP + h0) * WP + w0) * CIN;
    const unsigned short* wb = wT + ((size_t)(b * 9) * COUT + oc0) * CIN;

    // ---- per-thread gload source offsets (swizzled) ----
    int offA[6];
#pragma unroll
    for (int j = 0; j < 6; ++j) {
        int c    = (wid * 6 + j) * 64 + lane;          // [0,1536)
        int slot = c & 3;
        int o    = (c >> 2) & 127;
        int kh   = c >> 9;
        offA[j] = (int)((size_t)(kh * 3) * CCS) + o * CIN
                  + ((slot ^ ((o >> 1) & 3)) << 3);
    }

    f32x4 acc[4][8];
#pragma unroll
    for (int m = 0; m < 4; ++m)
#pragma unroll
        for (int n = 0; n < 8; ++n) acc[m][n] = (f32x4){0.f, 0.f, 0.f, 0.f};

    auto stage_A = [&](unsigned short* dst, const unsigned short* wsrc) {
#pragma unroll
        for (int j = 0; j < 6; ++j) {
            __builtin_amdgcn_global_load_lds(
                (const __attribute__((address_space(1))) void*)(wsrc + offA[j]),
                (__attribute__((address_space(3))) void*)(dst + (wid * 6 + j) * 512),
                16, 0, 0);
        }
    };
    auto stage_X = [&](int i0) {
#pragma unroll
        for (int j = 0; j < 6; ++j) {
            int g  = (wid * 6 + j) * 64 + lane;        // [0,1536)
            int gg = g < XCH ? g : 0;                  // clamp dummies
            int pix = gg >> 2, slot = gg & 3;
            int row = pix / XCOLS, col = pix - row * XCOLS;
            int ofx = (row * WP + col) * CIN + ((slot ^ ((col >> 1) & 3)) << 3);
            __builtin_amdgcn_global_load_lds(
                (const __attribute__((address_space(1))) void*)(xb + ofx + i0),
                (__attribute__((address_space(3))) void*)(lds_x + (wid * 6 + j) * 512),
                16, 0, 0);
        }
    };

    // ---- fragment read bases ----
    const int aoff = (wm * 64 + l15) * 32 + ((khalf ^ ((l15 >> 1) & 3)) << 3);

    bfrag aF[3][4];   // current phase's 12 A-frags (pipelined across phases)

    auto loadA = [&](const unsigned short* ab) {
#pragma unroll
        for (int kh = 0; kh < 3; ++kh)
#pragma unroll
            for (int m = 0; m < 4; ++m)
                aF[kh][m] = *(const bfrag*)(ab + aoff + ((size_t)kh * 128 + m * 16) * 32);
    };

    // kw-phase compute; abn = buffer holding NEXT phase's A-tile (staged at
    // phase p-1, drained by p-1's END vmcnt(0)+BAR -> all waves). Rows 7-9
    // reload aF in place right after each frag set's last use.
    auto compute = [&](int kw, const unsigned short* abn) {
        const int col = cw * 16 + l15 + kw;
        const unsigned short* bp = lds_x + col * 32 + ((khalf ^ ((col >> 1) & 3)) << 3);

        bfrag bs[3];
        bs[0] = *(const bfrag*)(bp);
        bs[1] = *(const bfrag*)(bp + (size_t)XCOLS * 32);

        __builtin_amdgcn_s_setprio(1);
#pragma unroll
        for (int r = 0; r < 10; ++r) {
            if (r < 8)
                bs[(r + 2) % 3] = *(const bfrag*)(bp + (size_t)(r + 2) * XCOLS * 32);
            const bfrag bv = bs[r % 3];
#pragma unroll
            for (int kh = 0; kh < 3; ++kh) {
                const int n = r - kh;
                if (n >= 0 && n < 8) {
#pragma unroll
                    for (int m = 0; m < 4; ++m)
                        acc[m][n] = __builtin_amdgcn_mfma_f32_16x16x32_bf16(
                            aF[kh][m], bv, acc[m][n], 0, 0, 0);
                }
            }
            if (r >= 7) {                   // aF[r-7] dead: reload for next phase
                const int kh = r - 7;
#pragma unroll
                for (int m = 0; m < 4; ++m)
                    aF[kh][m] = *(const bfrag*)(abn + aoff
                                  + ((size_t)kh * 128 + m * 16) * 32);
            }
        }
        __builtin_amdgcn_s_setprio(0);
    };

    // ---- prologue: X(0) + tile0 -> buf0; drain; aF <- tile0; tile1 -> buf1; drain
    stage_X(0);
    stage_A(lds_a[0], wb);                   // tile0 = A(kw0, c=0)
    ASM_VMCNT(0);
    BAR();
    loadA(lds_a[0]);                         // tile0 -> regs
    ASM_LGKM0();                             // my reads retired
    BAR();                                   // all waves' reads retired
    stage_A(lds_a[1], wb + 1 * CCS);         // tile1 = A(kw1,0) -> buf1
    ASM_VMCNT(0);                            // tile1 landed (mine)
    BAR();                                   // all waves' tile1 landed

    // Loop: phase p=3c+kw. stage tile(p+2) -> buf[p%2]; compute; end-drain.
#pragma unroll 1
    for (int c = 0; c < 8; ++c) {
        unsigned short* be = lds_a[c & 1];        // buf[p%2] at kw0 (p=3c)
        unsigned short* bo = lds_a[(c & 1) ^ 1];
        const size_t i0  = (size_t)c * 32;
        const size_t i0n = (size_t)((c + 1) & 7) * 32;  // c=7 -> dummy chunk 0

        // P0: stage tile(3c+2)=A(kw2,c)->be; compute reads tile(3c+1) from bo
        stage_A(be, wb + 2 * CCS + i0);
        __builtin_amdgcn_sched_barrier(0);
        compute(0, bo);
        ASM_LGKM0(); ASM_VMCNT(0);
        BAR();
        // P1: stage tile(3c+3)=A(kw0,c+1)->bo; compute reads tile(3c+2) from be
        stage_A(bo, wb + i0n);
        __builtin_amdgcn_sched_barrier(0);
        compute(1, be);
        ASM_LGKM0(); ASM_VMCNT(0);
        BAR();
        // P2: stage tile(3c+4)=A(kw1,c+1)->be; compute reads tile(3c+3) from bo
        stage_A(be, wb + 1 * CCS + i0n);
        __builtin_amdgcn_sched_barrier(0);
        compute(2, bo);
        ASM_LGKM0(); ASM_VMCNT(0);
        BAR();
        // chunk boundary: X(c) fully read (retired above); restage + drain
        if (c < 7) {
            stage_X((int)i0n);
            ASM_VMCNT(0);
            BAR();
        }
    }
    ASM_VMCNT(0);   // safety drain

    // ---- epilogue: leaky relu + store (C/D: col=lane&15 -> pixel, row -> oc)
#pragma unroll
    for (int m = 0; m < 4; ++m) {
#pragma unroll
        for (int n = 0; n < 8; ++n) {
            int h = h0 + n;
            int w = w0 + cw * 16 + l15;
#pragma unroll
            for (int r = 0; r < 4; ++r) {
                int oc = oc0 + wm * 64 + m * 16 + khalf * 4 + r;
                out[(((size_t)b * COUT + oc) * H_ + h) * W_ + w] = leaky(acc[m][n][r]);
            }
        }
    }
}

// ---------------------------------------------------------------------------
extern "C" void kernel_launch(void* const* d_in, const int* in_sizes, int n_in,
                              void* d_out, int out_size, void* d_ws, size_t ws_size,
                              hipStream_t stream) {
    const float* x      = (const float*)d_in[0];  // (8,256,128,128)
    const float* style  = (const float*)d_in[1];  // (8,256)
    const float* weight = (const float*)d_in[2];  // (256,256,3,3)
    float* out = (float*)d_out;                   // (8,256,128,128)

    // ws layout: S f32[768] @0 | demod f32[24] @4096 | wT bf16 @8192 (9.4MB)
    //            | xTpad bf16 @9445376 (69.2MB)   -> total ~78.7 MB
    float* S     = (float*)d_ws;
    float* demod = (float*)((char*)d_ws + 4096);
    unsigned short* wT = (unsigned short*)((char*)d_ws + 8192);
    unsigned short* xT = (unsigned short*)((char*)d_ws + 9445376);

    compute_S_kernel<<<CIN, 256, 0, stream>>>(weight, S);
    compute_demod_kernel<<<B_, 256, 0, stream>>>(style, S, demod);
    compute_wmodT_kernel<<<B_ * 9 * COUT, 256, 0, stream>>>(weight, style, demod, wT);
    transpose_kernel<<<dim3(32, H_ + 1, B_), 256, 0, stream>>>(x, xT);

    conv_mfma_kernel<<<dim3(1024), 256, 0, stream>>>(xT, wT, out);
}